// Round 1
// baseline (6479.416 us; speedup 1.0000x reference)
//
#include <hip/hip_runtime.h>
#include <hip/hip_bf16.h>
#include <stdint.h>

#define TT 512
#define BB 32
#define II 256
#define HH 512
#define OO 256
#define N4H 2048
#define CL_WGS 64
#define UPW 8
#define NCOL 32

typedef __attribute__((ext_vector_type(8))) short bf16x8;
typedef __attribute__((ext_vector_type(4))) float f32x4;

static __device__ __forceinline__ f32x4 MFMA(bf16x8 a, bf16x8 b, f32x4 c) {
  return __builtin_amdgcn_mfma_f32_16x16x32_bf16(a, b, c, 0, 0, 0);
}
static __device__ __forceinline__ unsigned short f2bf(float x) {
  union { float f; unsigned u; } v; v.f = x;
  unsigned r = v.u + 0x7FFFu + ((v.u >> 16) & 1u);
  return (unsigned short)(r >> 16);
}
static __device__ __forceinline__ float bf2f(unsigned short b) {
  union { unsigned u; float f; } v; v.u = ((unsigned)b) << 16; return v.f;
}
static __device__ __forceinline__ float sigm(float x) {
  return 1.0f / (1.0f + __expf(-x));
}
static __device__ __forceinline__ float tanh_(float x) {
  return 1.0f - 2.0f / (1.0f + __expf(2.0f * x));
}

// ---------------- prep kernels ----------------

// Split-convert row-major f32 [rows][K] into col-major bf16 hi/lo [N][K].
// packed: col c <- src row (c&3)*HH + (c>>2)  (i,f,g,o interleaved per unit)
__global__ void prep_w(const float* __restrict__ src, unsigned short* __restrict__ hi,
                       unsigned short* __restrict__ lo, int K, int N, int packed) {
  int tid = blockIdx.x * 256 + threadIdx.x;
  int nch = K >> 3;
  if (tid >= N * nch) return;
  int c = tid / nch;
  int j = (tid - c * nch) << 3;
  int row = packed ? ((c & 3) * HH + (c >> 2)) : c;
  const float* s = src + (size_t)row * K + j;
  alignas(16) unsigned short h8[8];
  alignas(16) unsigned short l8[8];
#pragma unroll
  for (int e = 0; e < 8; ++e) {
    float v = s[e];
    unsigned short hb = f2bf(v);
    h8[e] = hb;
    l8[e] = f2bf(v - bf2f(hb));
  }
  *(uint4*)(hi + (size_t)c * K + j) = *(const uint4*)h8;
  *(uint4*)(lo + (size_t)c * K + j) = *(const uint4*)l8;
}

__global__ void prep_bias(const float* __restrict__ bi0, const float* __restrict__ bh0,
                          const float* __restrict__ bim, const float* __restrict__ bhm,
                          float* __restrict__ bias0p, float* __restrict__ biasmp) {
  int c = blockIdx.x * 256 + threadIdx.x;
  if (c >= N4H) return;
  int row = (c & 3) * HH + (c >> 2);
  bias0p[c] = bi0[row] + bh0[row];
  biasmp[c] = bim[row] + bhm[row];
}

// inputs [B][T][I] f32 -> xb [(t*32+b)][I] bf16
__global__ void prep_x(const float* __restrict__ in, unsigned short* __restrict__ xb) {
  int tid = blockIdx.x * 256 + threadIdx.x;
  if (tid >= 16384 * 32) return;
  int row = tid >> 5, j = (tid & 31) << 3;
  int t = row >> 5, b = row & 31;
  const float* s = in + ((size_t)b * TT + t) * II + j;
  alignas(16) unsigned short o8[8];
#pragma unroll
  for (int e = 0; e < 8; ++e) o8[e] = f2bf(s[e]);
  *(uint4*)(xb + (size_t)row * II + j) = *(const uint4*)o8;
}

// ---------------- big GEMMs ----------------

// gates0_x[16384][2048] = xb @ Wih_in^T (hi+lo) + bias0p   (cols packed u*4+g)
__global__ __launch_bounds__(256) void gemm_g0(
    const unsigned short* __restrict__ A, const unsigned short* __restrict__ Bhi,
    const unsigned short* __restrict__ Blo, const float* __restrict__ biasp,
    float* __restrict__ out) {
  const int K = II;
  int wgm = blockIdx.x & 255;
  int wgn = blockIdx.x >> 8;
  int l = threadIdx.x & 63, wave = threadIdx.x >> 6;
  int mbase = wgm * 64 + wave * 16;
  int nbase = wgn * 64;
  int arow = mbase + (l & 15);
  int koff = (l >> 4) * 8;
  f32x4 acc[4] = {};
  for (int kt = 0; kt < K / 32; ++kt) {
    bf16x8 a = *(const bf16x8*)(A + (size_t)arow * K + kt * 32 + koff);
#pragma unroll
    for (int n = 0; n < 4; ++n) {
      int col = nbase + n * 16 + (l & 15);
      bf16x8 bh = *(const bf16x8*)(Bhi + (size_t)col * K + kt * 32 + koff);
      bf16x8 bl = *(const bf16x8*)(Blo + (size_t)col * K + kt * 32 + koff);
      acc[n] = MFMA(a, bh, acc[n]);
      acc[n] = MFMA(a, bl, acc[n]);
    }
  }
#pragma unroll
  for (int n = 0; n < 4; ++n) {
    int col = nbase + n * 16 + (l & 15);
    float bv = biasp[col];
#pragma unroll
    for (int r = 0; r < 4; ++r) {
      int row = mbase + (l >> 4) * 4 + r;
      out[(size_t)row * N4H + col] = acc[n][r] + bv;
    }
  }
}

// y[b][t][o] = out1 @ fc_w^T (hi+lo) + fc_b
__global__ __launch_bounds__(256) void gemm_fc(
    const unsigned short* __restrict__ A, const unsigned short* __restrict__ Bhi,
    const unsigned short* __restrict__ Blo, const float* __restrict__ bias,
    float* __restrict__ y) {
  const int K = 2 * HH;
  int wgm = blockIdx.x & 255;
  int wgn = blockIdx.x >> 8;
  int l = threadIdx.x & 63, wave = threadIdx.x >> 6;
  int mbase = wgm * 64 + wave * 16;
  int nbase = wgn * 64;
  int arow = mbase + (l & 15);
  int koff = (l >> 4) * 8;
  f32x4 acc[4] = {};
  for (int kt = 0; kt < K / 32; ++kt) {
    bf16x8 a = *(const bf16x8*)(A + (size_t)arow * K + kt * 32 + koff);
#pragma unroll
    for (int n = 0; n < 4; ++n) {
      int col = nbase + n * 16 + (l & 15);
      bf16x8 bh = *(const bf16x8*)(Bhi + (size_t)col * K + kt * 32 + koff);
      bf16x8 bl = *(const bf16x8*)(Blo + (size_t)col * K + kt * 32 + koff);
      acc[n] = MFMA(a, bh, acc[n]);
      acc[n] = MFMA(a, bl, acc[n]);
    }
  }
#pragma unroll
  for (int n = 0; n < 4; ++n) {
    int col = nbase + n * 16 + (l & 15);
    float bv = bias[col];
#pragma unroll
    for (int r = 0; r < 4; ++r) {
      int row = mbase + (l >> 4) * 4 + r;
      int t = row >> 5, b = row & 31;
      y[((size_t)b * TT + t) * OO + col] = acc[n][r] + bv;
    }
  }
}

// ---------------- scan helpers ----------------

// stage 32 packed cols x 512 K bf16 from col-major global into XOR-swizzled LDS
static __device__ void stage_w_lds(const unsigned short* __restrict__ g, int c0,
                                   unsigned short* __restrict__ lds) {
  int cl = threadIdx.x >> 3;
  int sub = threadIdx.x & 7;
  const uint4* src = (const uint4*)(g + (size_t)(c0 + cl) * HH);
  for (int j = sub; j < 64; j += 8) {
    uint4 v = src[j];
    int off = cl * 1024 + ((j ^ (cl & 7)) << 4);
    *(uint4*)((char*)lds + off) = v;
  }
}
static __device__ __forceinline__ bf16x8 lds_bfrag(const unsigned short* lds, int cl, int kc) {
  int off = cl * 1024 + ((kc ^ (cl & 7)) << 4);
  return *(const bf16x8*)((const char*)lds + off);
}
static __device__ __forceinline__ void cluster_wait(unsigned int* f, unsigned tgt) {
  if (threadIdx.x < CL_WGS) {
    while (true) {
      unsigned v = __hip_atomic_load(f + threadIdx.x, __ATOMIC_RELAXED, __HIP_MEMORY_SCOPE_AGENT);
      if (__all((int)(v >= tgt))) break;
    }
  }
  __syncthreads();
}

// ---------------- layer-0 scan ----------------
__global__ void __launch_bounds__(256, 1) scan_l0(
    const unsigned short* __restrict__ Whi, const unsigned short* __restrict__ Wlo,
    const float* __restrict__ g0x, unsigned short* __restrict__ h0,
    unsigned int* __restrict__ flags) {
  extern __shared__ char smem[];
  unsigned short* whi = (unsigned short*)smem;
  unsigned short* wlo = (unsigned short*)(smem + 32768);
  unsigned short* hst = (unsigned short*)(smem + 65536);
  const int dir = blockIdx.x >> 6;
  const int wg = blockIdx.x & 63;
  const int tid = threadIdx.x;
  const int l = tid & 63;
  const int wave = tid >> 6;
  stage_w_lds(Whi, wg * NCOL, whi);
  stage_w_lds(Wlo, wg * NCOL, wlo);
  __syncthreads();
  const int mt = wave & 1, nt = wave >> 1;
  const int lc = nt * 16 + (l & 15);
  const int gate = lc & 3;
  const int ulocal = lc >> 2;
  const int rowb = mt * 16 + ((l >> 4) << 2);
  const int arow = mt * 16 + (l & 15);
  const int koff = (l >> 4) * 8;
  unsigned int* myf = flags + dir * CL_WGS;
  float cprev[4] = {0.f, 0.f, 0.f, 0.f};
  for (int t = 0; t < TT; ++t) {
    const int tin = dir ? (TT - 1 - t) : t;
    float gx[4];
#pragma unroll
    for (int r = 0; r < 4; ++r)
      gx[r] = g0x[((size_t)tin * BB + rowb + r) * N4H + wg * NCOL + lc];
    f32x4 acc0 = {}, acc1 = {};
    if (t > 0) {
      cluster_wait(myf, (unsigned)t);
      const unsigned short* hp =
          h0 + (size_t)(dir * TT + (t - 1)) * BB * HH + (size_t)arow * HH + koff;
#pragma unroll
      for (int kt = 0; kt < 16; ++kt) {
        bf16x8 a = *(const bf16x8*)(hp + kt * 32);
        acc0 = MFMA(a, lds_bfrag(whi, lc, kt * 4 + (l >> 4)), acc0);
        acc1 = MFMA(a, lds_bfrag(wlo, lc, kt * 4 + (l >> 4)), acc1);
      }
    }
    float hnew[4];
#pragma unroll
    for (int r = 0; r < 4; ++r) {
      float pre = acc0[r] + acc1[r] + gx[r];
      float own = (gate == 2) ? tanh_(pre) : sigm(pre);
      int q = l & 60;
      float iv = __shfl(own, q + 0, 64);
      float fv = __shfl(own, q + 1, 64);
      float gv = __shfl(own, q + 2, 64);
      float ov = __shfl(own, q + 3, 64);
      float cn = fv * cprev[r] + iv * gv;
      cprev[r] = cn;
      hnew[r] = ov * tanh_(cn);
    }
    if (gate == 0) {
#pragma unroll
      for (int r = 0; r < 4; ++r) hst[(rowb + r) * UPW + ulocal] = f2bf(hnew[r]);
    }
    __syncthreads();
    if (tid < 64) {
      unsigned long long v = *(const unsigned long long*)(hst + tid * 4);
      size_t off = ((size_t)(dir * TT + t) * BB + (tid >> 1)) * HH + wg * UPW + (tid & 1) * 4;
      __hip_atomic_store((unsigned long long*)(h0 + off), v, __ATOMIC_RELAXED,
                         __HIP_MEMORY_SCOPE_AGENT);
    }
    __syncthreads();
    if (tid == 0)
      __hip_atomic_store(myf + wg, (unsigned)(t + 1), __ATOMIC_RELAXED, __HIP_MEMORY_SCOPE_AGENT);
  }
}

// ---------------- layer-1 scan (fused input GEMM + outputs) ----------------
__global__ void __launch_bounds__(256, 1) scan_l1(
    const unsigned short* __restrict__ Xhi, const unsigned short* __restrict__ Xlo,
    const unsigned short* __restrict__ Rhi, const unsigned short* __restrict__ Rlo,
    const unsigned short* __restrict__ h0, const float* __restrict__ biasp,
    unsigned short* __restrict__ out1, float* __restrict__ gates, float* __restrict__ hn,
    unsigned int* __restrict__ flags) {
  extern __shared__ char smem[];
  unsigned short* xhi = (unsigned short*)smem;
  unsigned short* xlo = (unsigned short*)(smem + 32768);
  unsigned short* rhi = (unsigned short*)(smem + 65536);
  unsigned short* rlo = (unsigned short*)(smem + 98304);
  unsigned short* hst = (unsigned short*)(smem + 131072);
  const int dir = blockIdx.x >> 6;
  const int wg = blockIdx.x & 63;
  const int tid = threadIdx.x;
  const int l = tid & 63;
  const int wave = tid >> 6;
  stage_w_lds(Xhi, wg * NCOL, xhi);
  stage_w_lds(Xlo, wg * NCOL, xlo);
  stage_w_lds(Rhi, wg * NCOL, rhi);
  stage_w_lds(Rlo, wg * NCOL, rlo);
  __syncthreads();
  const int mt = wave & 1, nt = wave >> 1;
  const int lc = nt * 16 + (l & 15);
  const int gate = lc & 3;
  const int ulocal = lc >> 2;
  const int ug = wg * UPW + ulocal;
  const int rowb = mt * 16 + ((l >> 4) << 2);
  const int arow = mt * 16 + (l & 15);
  const int koff = (l >> 4) * 8;
  unsigned int* myf = flags + dir * CL_WGS;
  const float bias = biasp[wg * NCOL + lc];
  float cprev[4] = {0.f, 0.f, 0.f, 0.f};
  for (int t = 0; t < TT; ++t) {
    f32x4 acc0 = {}, acc1 = {};
    {
      const unsigned short* xp =
          h0 + (size_t)(dir * TT + t) * BB * HH + (size_t)arow * HH + koff;
#pragma unroll
      for (int kt = 0; kt < 16; ++kt) {
        bf16x8 a = *(const bf16x8*)(xp + kt * 32);
        acc0 = MFMA(a, lds_bfrag(xhi, lc, kt * 4 + (l >> 4)), acc0);
        acc1 = MFMA(a, lds_bfrag(xlo, lc, kt * 4 + (l >> 4)), acc1);
      }
    }
    if (t > 0) {
      cluster_wait(myf, (unsigned)t);
      const unsigned short* hp = out1 + (size_t)(t - 1) * BB * 2 * HH +
                                 (size_t)arow * 2 * HH + dir * HH + koff;
#pragma unroll
      for (int kt = 0; kt < 16; ++kt) {
        bf16x8 a = *(const bf16x8*)(hp + kt * 32);
        acc0 = MFMA(a, lds_bfrag(rhi, lc, kt * 4 + (l >> 4)), acc0);
        acc1 = MFMA(a, lds_bfrag(rlo, lc, kt * 4 + (l >> 4)), acc1);
      }
    }
    float hnew[4];
#pragma unroll
    for (int r = 0; r < 4; ++r) {
      float pre = acc0[r] + acc1[r] + bias;
      float own = (gate == 2) ? tanh_(pre) : sigm(pre);
      gates[(((size_t)t * 4 + gate) * BB + rowb + r) * (2 * HH) + dir * HH + ug] = own;
      int q = l & 60;
      float iv = __shfl(own, q + 0, 64);
      float fv = __shfl(own, q + 1, 64);
      float gv = __shfl(own, q + 2, 64);
      float ov = __shfl(own, q + 3, 64);
      float cn = fv * cprev[r] + iv * gv;
      cprev[r] = cn;
      if (gate == 1) hn[((size_t)t * BB + rowb + r) * (2 * HH) + dir * HH + ug] = cn;
      hnew[r] = ov * tanh_(cn);
    }
    if (gate == 0) {
#pragma unroll
      for (int r = 0; r < 4; ++r) hst[(rowb + r) * UPW + ulocal] = f2bf(hnew[r]);
    }
    __syncthreads();
    if (tid < 64) {
      unsigned long long v = *(const unsigned long long*)(hst + tid * 4);
      size_t off = ((size_t)t * BB + (tid >> 1)) * (2 * HH) + dir * HH + wg * UPW + (tid & 1) * 4;
      __hip_atomic_store((unsigned long long*)(out1 + off), v, __ATOMIC_RELAXED,
                         __HIP_MEMORY_SCOPE_AGENT);
    }
    __syncthreads();
    if (tid == 0)
      __hip_atomic_store(myf + wg, (unsigned)(t + 1), __ATOMIC_RELAXED, __HIP_MEMORY_SCOPE_AGENT);
  }
}

// ---------------- host ----------------
extern "C" void kernel_launch(void* const* d_in, const int* in_sizes, int n_in,
                              void* d_out, int out_size, void* d_ws, size_t ws_size,
                              hipStream_t stream) {
  const float* inputs   = (const float*)d_in[0];
  const float* w_ih_in  = (const float*)d_in[1];
  const float* w_hh_in  = (const float*)d_in[2];
  const float* b_ih_in  = (const float*)d_in[3];
  const float* b_hh_in  = (const float*)d_in[4];
  const float* w_ih_mid = (const float*)d_in[5];
  const float* w_hh_mid = (const float*)d_in[6];
  const float* b_ih_mid = (const float*)d_in[7];
  const float* b_hh_mid = (const float*)d_in[8];
  const float* fc_w     = (const float*)d_in[9];
  const float* fc_b     = (const float*)d_in[10];

  char* p = (char*)d_ws;
  auto take = [&](size_t n) { char* q = p; p += (n + 255) & ~(size_t)255; return q; };
  unsigned short* xb        = (unsigned short*)take((size_t)16384 * II * 2);
  unsigned short* wihin_hi  = (unsigned short*)take((size_t)N4H * II * 2);
  unsigned short* wihin_lo  = (unsigned short*)take((size_t)N4H * II * 2);
  unsigned short* whhin_hi  = (unsigned short*)take((size_t)N4H * HH * 2);
  unsigned short* whhin_lo  = (unsigned short*)take((size_t)N4H * HH * 2);
  unsigned short* wihmid_hi = (unsigned short*)take((size_t)N4H * HH * 2);
  unsigned short* wihmid_lo = (unsigned short*)take((size_t)N4H * HH * 2);
  unsigned short* whhmid_hi = (unsigned short*)take((size_t)N4H * HH * 2);
  unsigned short* whhmid_lo = (unsigned short*)take((size_t)N4H * HH * 2);
  unsigned short* fchi      = (unsigned short*)take((size_t)OO * 2 * HH * 2);
  unsigned short* fclo      = (unsigned short*)take((size_t)OO * 2 * HH * 2);
  float* bias0p             = (float*)take((size_t)N4H * 4);
  float* biasmp             = (float*)take((size_t)N4H * 4);
  float* g0x                = (float*)take((size_t)16384 * N4H * 4);
  unsigned short* h0        = (unsigned short*)take((size_t)2 * TT * BB * HH * 2);
  unsigned short* out1      = (unsigned short*)take((size_t)TT * BB * 2 * HH * 2);
  unsigned int* flags       = (unsigned int*)take(4096);

  float* y_out     = (float*)d_out;
  float* gates_out = y_out + (size_t)BB * TT * OO;
  float* hn_out    = gates_out + (size_t)TT * 4 * BB * 2 * HH;

  hipMemsetAsync(flags, 0, 4096, stream);
  hipFuncSetAttribute(reinterpret_cast<const void*>(scan_l0),
                      hipFuncAttributeMaxDynamicSharedMemorySize, 90112);
  hipFuncSetAttribute(reinterpret_cast<const void*>(scan_l1),
                      hipFuncAttributeMaxDynamicSharedMemorySize, 131584);

  prep_w<<<256, 256, 0, stream>>>(w_ih_in, wihin_hi, wihin_lo, II, N4H, 1);
  prep_w<<<512, 256, 0, stream>>>(w_hh_in, whhin_hi, whhin_lo, HH, N4H, 1);
  prep_w<<<512, 256, 0, stream>>>(w_ih_mid, wihmid_hi, wihmid_lo, HH, N4H, 1);
  prep_w<<<512, 256, 0, stream>>>(w_hh_mid, whhmid_hi, whhmid_lo, HH, N4H, 1);
  prep_w<<<128, 256, 0, stream>>>(fc_w, fchi, fclo, 2 * HH, OO, 0);
  prep_bias<<<8, 256, 0, stream>>>(b_ih_in, b_hh_in, b_ih_mid, b_hh_mid, bias0p, biasmp);
  prep_x<<<2048, 256, 0, stream>>>(inputs, xb);
  gemm_g0<<<8192, 256, 0, stream>>>(xb, wihin_hi, wihin_lo, bias0p, g0x);
  scan_l0<<<128, 256, 90112, stream>>>(whhin_hi, whhin_lo, g0x, h0, flags);
  scan_l1<<<128, 256, 131584, stream>>>(wihmid_hi, wihmid_lo, whhmid_hi, whhmid_lo, h0, biasmp,
                                        out1, gates_out, hn_out, flags + 128);
  gemm_fc<<<1024, 256, 0, stream>>>(out1, fchi, fclo, fc_b, y_out);
}